// Round 8
// baseline (192.831 us; speedup 1.0000x reference)
//
#include <hip/hip_runtime.h>
#include <hip/hip_bf16.h>

#define BB 64
#define CC 512
#define NPIX 784
#define KK 32
#define NSPL 13
#define PXB 64             // px per block
#define NCHK 8             // phase-1 c-chunks of 64
#define XS2_S 72           // phase-2 xs / A_l stride (shorts): 36 dw == 4 mod 32

typedef __attribute__((ext_vector_type(8))) short short8;
typedef __attribute__((ext_vector_type(4))) float floatx4;
typedef __attribute__((ext_vector_type(4))) unsigned short ushort4v;

// ws layout (float offsets)
#define OFF_BF  0                          // cw B-frags bf16: 2048 slots x 8 shorts = 8192 floats
#define OFF_CSQ 8192                       // csq: 32 floats
#define OFF_WP  8256                       // W_p [13][64][32][512] fp32
#define OFF_WS2 (OFF_WP + NSPL*BB*KK*CC)   // wsum_p [13][64][32]

__device__ __forceinline__ unsigned short f2bf(float f) {
    union { float f; unsigned u; } v; v.f = f;
    return (unsigned short)((v.u + 0x7FFFu + ((v.u >> 16) & 1u)) >> 16);
}
__device__ __forceinline__ float bf2f(unsigned short h) {
    union { unsigned u; float f; } v; v.u = ((unsigned)h) << 16; return v.f;
}

// ---------------------------------------------------------------------------
// kprep: bake cw into MFMA B-fragment layout (bf16) + csq (fp32).
// Frag slot idx = (kc*2+half)*64 + lane holds cw[half*16+(lane&15)]
//                 [kc*32+(lane>>4)*8 .. +8].  blocks 0..7: Bf; block 8: csq.
// ---------------------------------------------------------------------------
__global__ __launch_bounds__(256) void kprep(const float* __restrict__ cw,
                                             float* __restrict__ ws)
{
    const int t = threadIdx.x;
    if (blockIdx.x < 8) {
        const int idx  = blockIdx.x * 256 + t;   // 0..2047
        const int lane = idx & 63;
        const int pair = idx >> 6;               // kc*2+half
        const int row  = (pair & 1) * 16 + (lane & 15);
        const int cb   = (pair >> 1) * 32 + (lane >> 4) * 8;
        unsigned short* Bf = (unsigned short*)(ws + OFF_BF);
        ushort4v pa, pb;
        pa.x = f2bf(cw[row * CC + cb + 0]); pa.y = f2bf(cw[row * CC + cb + 1]);
        pa.z = f2bf(cw[row * CC + cb + 2]); pa.w = f2bf(cw[row * CC + cb + 3]);
        pb.x = f2bf(cw[row * CC + cb + 4]); pb.y = f2bf(cw[row * CC + cb + 5]);
        pb.z = f2bf(cw[row * CC + cb + 6]); pb.w = f2bf(cw[row * CC + cb + 7]);
        *(ushort4v*)&Bf[(size_t)idx * 8]     = pa;
        *(ushort4v*)&Bf[(size_t)idx * 8 + 4] = pb;
    } else {
        __shared__ float red[8][KK];
        const int k = t & 31, part = t >> 5;
        float s = 0.f;
#pragma unroll 4
        for (int i = 0; i < 64; ++i) {
            const float v = cw[k * CC + part * 64 + i];
            s += v * v;
        }
        red[part][k] = s;
        __syncthreads();
        if (t < KK) {
            float s2 = 0.f;
#pragma unroll
            for (int p = 0; p < 8; ++p) s2 += red[p][t];
            ws[OFF_CSQ + t] = s2;
        }
    }
}

// ---------------------------------------------------------------------------
// k_fused: per (split, batch) block of 64 px. 832 blocks, 4 waves.
//  Phase 1: x staged fp32 [64c][64px] via global_load_lds (double-buffered);
//           frag-read from LDS; cw B-frags from global (kprep layout, L2-hot);
//           softmax fused; A -> LDS [k][px] bf16.
//  Phase 2: W_p[k][c] = sum_px A[k][px] x[c][px] via MFMA (x re-read, L2-hot).
// ---------------------------------------------------------------------------
__global__ __launch_bounds__(256) void k_fused(const float* __restrict__ x,
                                               const float* __restrict__ scale,
                                               float* __restrict__ ws)
{
    __shared__ __align__(16) float xbuf[2][64 * 64];           // 32768 B
    __shared__ __align__(16) unsigned short A_l[KK * XS2_S];   //  4608 B
    __shared__ float wred[KK][8];                              //  1024 B

    const int t     = threadIdx.x;
    const int lane  = t & 63;
    const int w     = t >> 6;
    const int col   = lane & 15;
    const int quad  = lane >> 4;
    const int split = blockIdx.x;
    const int b     = blockIdx.y;
    const int p0    = split * PXB;

    const unsigned short* Bf = (const unsigned short*)(ws + OFF_BF);
    const float* xlim = x + (size_t)BB * CC * NPIX - 4;   // last safe float4 start

    // ---- async stage chunk ch (64 c-rows x 64 px) into xbuf[buf] ----
    auto stage = [&](int ch, int buf) {
#pragma unroll
        for (int i = 0; i < 4; ++i) {
            const int r0 = w * 16 + i * 4;                     // wave-uniform row base
            const float* g = x + ((size_t)b * CC + ch * 64 + r0 + (lane >> 4)) * NPIX
                               + p0 + (lane & 15) * 4;
            if (g > xlim) g = xlim;                            // split-12 pad clamp
            __builtin_amdgcn_global_load_lds(
                (const __attribute__((address_space(1))) void*)g,
                (__attribute__((address_space(3))) void*)&xbuf[buf][r0 * 64],
                16, 0, 0);
        }
    };

    // ================= Phase 1 =================
    floatx4 acc0 = {0.f, 0.f, 0.f, 0.f};
    floatx4 acc1 = {0.f, 0.f, 0.f, 0.f};
    float xsqp = 0.f;

    stage(0, 0);
    for (int ch = 0; ch < NCHK; ++ch) {
        __syncthreads();                       // stage(ch) complete; prev reads done
        if (ch + 1 < NCHK) stage(ch + 1, (ch + 1) & 1);
        const float* xb = xbuf[ch & 1];
#pragma unroll
        for (int ks = 0; ks < 2; ++ks) {
            const int kc = ch * 2 + ks;
            float v[8];
#pragma unroll
            for (int j = 0; j < 8; ++j)
                v[j] = xb[(ks * 32 + quad * 8 + j) * 64 + w * 16 + col];
#pragma unroll
            for (int j = 0; j < 8; ++j) xsqp += v[j] * v[j];
            short8 a;
#pragma unroll
            for (int j = 0; j < 8; ++j) a[j] = (short)f2bf(v[j]);
            const short8 b0 = *(const short8*)&Bf[(size_t)((kc * 2 + 0) * 64 + lane) * 8];
            const short8 b1 = *(const short8*)&Bf[(size_t)((kc * 2 + 1) * 64 + lane) * 8];
            acc0 = __builtin_amdgcn_mfma_f32_16x16x32_bf16(a, b0, acc0, 0, 0, 0);
            acc1 = __builtin_amdgcn_mfma_f32_16x16x32_bf16(a, b1, acc1, 0, 0, 0);
        }
    }

    // xsq across quad c-slices
    xsqp += __shfl_xor(xsqp, 16);
    xsqp += __shfl_xor(xsqp, 32);

    // ---- fused softmax; A_l zeroed for pad px (split 12) ----
    const float s0 = scale[col], s1 = scale[col + 16];
    const float q0 = ws[OFF_CSQ + col], q1 = ws[OFF_CSQ + col + 16];
#pragma unroll
    for (int r = 0; r < 4; ++r) {
        const int pl = w * 16 + quad * 4 + r;
        const float xq = __shfl(xsqp, quad * 4 + r);
        const float d0 = s0 * (xq + q0 - 2.f * acc0[r]);
        const float d1 = s1 * (xq + q1 - 2.f * acc1[r]);
        float mx = fmaxf(d0, d1);
        mx = fmaxf(mx, __shfl_xor(mx, 1));
        mx = fmaxf(mx, __shfl_xor(mx, 2));
        mx = fmaxf(mx, __shfl_xor(mx, 4));
        mx = fmaxf(mx, __shfl_xor(mx, 8));
        const float e0 = __expf(d0 - mx), e1 = __expf(d1 - mx);
        float sm = e0 + e1;
        sm += __shfl_xor(sm, 1);
        sm += __shfl_xor(sm, 2);
        sm += __shfl_xor(sm, 4);
        sm += __shfl_xor(sm, 8);
        const float inv = 1.f / sm;
        const bool valid = (p0 + pl) < NPIX;
        A_l[col * XS2_S + pl]        = valid ? f2bf(e0 * inv) : (unsigned short)0;
        A_l[(col + 16) * XS2_S + pl] = valid ? f2bf(e1 * inv) : (unsigned short)0;
    }
    __syncthreads();   // A_l complete; xbuf free

    // ---- wsum partials ----
    {
        const int k = t >> 3, part = t & 7;
        float s = 0.f;
#pragma unroll
        for (int i = 0; i < 8; ++i) s += bf2f(A_l[k * XS2_S + part * 8 + i]);
        wred[k][part] = s;
    }
    __syncthreads();
    if (t < KK) {
        float s = 0.f;
#pragma unroll
        for (int p = 0; p < 8; ++p) s += wred[t][p];
        ws[OFF_WS2 + (size_t)(split * BB + b) * KK + t] = s;
    }

    // ================= Phase 2 =================
    unsigned short* xs = (unsigned short*)&xbuf[0][0];   // [128][XS2_S] bf16, 18432 B
    const float* xbase = x + (size_t)b * CC * NPIX + p0;
    float* Wp = ws + OFF_WP;

    for (int cch = 0; cch < 4; ++cch) {
        __syncthreads();
        // stage x chunk [128 c][64 px] -> bf16 (2048 float4 = 8/thread)
#pragma unroll 2
        for (int j = 0; j < 8; ++j) {
            const int q = t + j * 256;
            const int row = q >> 4, pq = q & 15;
            ushort4v p;
            if (p0 + pq * 4 < NPIX) {
                const float4 v = *(const float4*)&xbase[(size_t)(cch * 128 + row) * NPIX + pq * 4];
                p.x = f2bf(v.x); p.y = f2bf(v.y); p.z = f2bf(v.z); p.w = f2bf(v.w);
            } else { p.x = 0; p.y = 0; p.z = 0; p.w = 0; }
            *(ushort4v*)&xs[row * XS2_S + pq * 4] = p;
        }
        __syncthreads();

        floatx4 a00 = {0.f,0.f,0.f,0.f}, a01 = {0.f,0.f,0.f,0.f};
        floatx4 a10 = {0.f,0.f,0.f,0.f}, a11 = {0.f,0.f,0.f,0.f};
#pragma unroll
        for (int ks = 0; ks < 2; ++ks) {
            const int off = ks * 32 + quad * 8;
            const short8 av0 = *(const short8*)&A_l[col * XS2_S + off];
            const short8 av1 = *(const short8*)&A_l[(col + 16) * XS2_S + off];
            const short8 bv0 = *(const short8*)&xs[(w * 32 + col) * XS2_S + off];
            const short8 bv1 = *(const short8*)&xs[(w * 32 + 16 + col) * XS2_S + off];
            a00 = __builtin_amdgcn_mfma_f32_16x16x32_bf16(av0, bv0, a00, 0, 0, 0);
            a10 = __builtin_amdgcn_mfma_f32_16x16x32_bf16(av1, bv0, a10, 0, 0, 0);
            a01 = __builtin_amdgcn_mfma_f32_16x16x32_bf16(av0, bv1, a01, 0, 0, 0);
            a11 = __builtin_amdgcn_mfma_f32_16x16x32_bf16(av1, bv1, a11, 0, 0, 0);
        }

        const size_t sb = (size_t)(split * BB + b) * KK;
        const int cb = cch * 128 + w * 32;
#pragma unroll
        for (int r = 0; r < 4; ++r) {
            const int k0 = quad * 4 + r;
            Wp[(sb + k0) * CC + cb + col]           = a00[r];
            Wp[(sb + k0) * CC + cb + 16 + col]      = a01[r];
            Wp[(sb + k0 + 16) * CC + cb + col]      = a10[r];
            Wp[(sb + k0 + 16) * CC + cb + 16 + col] = a11[r];
        }
    }
}

// ---------------------------------------------------------------------------
// k3: out[b][k][c] = sum_s W_p[s][b][k][c] - (sum_s wsum_p[s][b][k]) * cw[k][c]
// ---------------------------------------------------------------------------
__global__ __launch_bounds__(256) void k3(const float* __restrict__ cw,
                                          const float* __restrict__ ws,
                                          float* __restrict__ out)
{
    const int idx = blockIdx.x * 256 + threadIdx.x;   // 262144 float4s
    const int c4 = idx & 127;
    const int k  = (idx >> 7) & 31;
    const int b  = idx >> 12;

    const float* Wp = ws + OFF_WP;
    float4 s = make_float4(0.f, 0.f, 0.f, 0.f);
#pragma unroll
    for (int sp = 0; sp < NSPL; ++sp) {
        const float4 v = *(const float4*)&Wp[((size_t)(sp * BB + b) * KK + k) * CC + c4 * 4];
        s.x += v.x; s.y += v.y; s.z += v.z; s.w += v.w;
    }
    float wsum = 0.f;
#pragma unroll
    for (int sp = 0; sp < NSPL; ++sp) wsum += ws[OFF_WS2 + (size_t)(sp * BB + b) * KK + k];

    const float4 c4f = *(const float4*)&cw[k * CC + c4 * 4];
    float4 o;
    o.x = s.x - wsum * c4f.x;
    o.y = s.y - wsum * c4f.y;
    o.z = s.z - wsum * c4f.z;
    o.w = s.w - wsum * c4f.w;
    *(float4*)&out[(size_t)idx * 4] = o;
}

extern "C" void kernel_launch(void* const* d_in, const int* in_sizes, int n_in,
                              void* d_out, int out_size, void* d_ws, size_t ws_size,
                              hipStream_t stream) {
    const float* x     = (const float*)d_in[0];   // (64, 512, 28, 28)
    const float* cw    = (const float*)d_in[1];   // (32, 512)
    const float* scale = (const float*)d_in[2];   // (32,)
    float* out = (float*)d_out;                   // (64, 32, 512)
    float* ws  = (float*)d_ws;

    kprep<<<dim3(9), dim3(256), 0, stream>>>(cw, ws);
    k_fused<<<dim3(NSPL, BB), dim3(256), 0, stream>>>(x, scale, ws);
    k3<<<dim3(BB * KK * CC / 4 / 256), dim3(256), 0, stream>>>(cw, ws, out);
}